// Round 10
// baseline (400.428 us; speedup 1.0000x reference)
//
#include <hip/hip_runtime.h>
#include <hip/hip_bf16.h>
#include <math.h>

// Problem constants (fixed by the reference)
#define DIMN   1024
#define HEADS  16
#define DHEAD  64
#define BQKV   3072
#define BATCH  4
#define SEQ    1024
#define NROWS  (BATCH * SEQ)     // 4096
#define ATT_SCALE 0.125f         // 1/sqrt(64), exact power of two
#define LN_EPS 1e-5f

typedef __attribute__((ext_vector_type(8))) short  bf16x8;
typedef __attribute__((ext_vector_type(4))) float  f32x4;
typedef __attribute__((ext_vector_type(4))) unsigned short u16x4;

// fp32 -> bf16 round-to-nearest-even
__device__ __forceinline__ unsigned short f2bf(float f) {
    unsigned u = __float_as_uint(f);
    u += 0x7FFFu + ((u >> 16) & 1u);
    return (unsigned short)(u >> 16);
}
__device__ __forceinline__ float bf2f(unsigned short h) {
    return __uint_as_float((unsigned)h << 16);
}
// async global->LDS 16B copy (wave-uniform dest = base + lane*16)
__device__ __forceinline__ void gload_lds16(const void* g, void* l) {
    __builtin_amdgcn_global_load_lds(
        (const __attribute__((address_space(1))) unsigned int*)g,
        (__attribute__((address_space(3))) unsigned int*)l, 16, 0, 0);
}

// ---------------------------------------------------------------------------
// Kernel 1: svd_adapt[d] = sigma * sum_r U[d,r] * (sum_j V[r,j])
// ---------------------------------------------------------------------------
__global__ __launch_bounds__(1024) void svd_kernel(
    const float* __restrict__ U, const float* __restrict__ V,
    const float* __restrict__ sigma_p, float* __restrict__ svd)
{
    __shared__ float part[16][4];
    __shared__ float vsum[4];
    const int tid = threadIdx.x;          // 0..1023
    float v0 = V[0 * DIMN + tid];
    float v1 = V[1 * DIMN + tid];
    float v2 = V[2 * DIMN + tid];
    float v3 = V[3 * DIMN + tid];
    #pragma unroll
    for (int off = 32; off > 0; off >>= 1) {
        v0 += __shfl_down(v0, off);
        v1 += __shfl_down(v1, off);
        v2 += __shfl_down(v2, off);
        v3 += __shfl_down(v3, off);
    }
    const int lane = tid & 63, w = tid >> 6;
    if (lane == 0) { part[w][0] = v0; part[w][1] = v1; part[w][2] = v2; part[w][3] = v3; }
    __syncthreads();
    if (tid < 4) {
        float s = 0.f;
        #pragma unroll
        for (int i = 0; i < 16; ++i) s += part[i][tid];
        vsum[tid] = s;
    }
    __syncthreads();
    const float sg = sigma_p[0];
    float acc = U[tid * 4 + 0] * vsum[0] + U[tid * 4 + 1] * vsum[1]
              + U[tid * 4 + 2] * vsum[2] + U[tid * 4 + 3] * vsum[3];
    svd[tid] = sg * acc;
}

// ---------------------------------------------------------------------------
// Kernel 1b: fp32 -> bf16 bulk convert (n multiple of 2048) — Wout only now
// ---------------------------------------------------------------------------
__global__ __launch_bounds__(256) void cvt_kernel(
    const float* __restrict__ src, unsigned short* __restrict__ dst)
{
    const int i = (blockIdx.x * 256 + threadIdx.x) * 8;
    float4 a = *(const float4*)(src + i);
    float4 b = *(const float4*)(src + i + 4);
    u16x4 h0, h1;
    h0[0] = f2bf(a.x); h0[1] = f2bf(a.y); h0[2] = f2bf(a.z); h0[3] = f2bf(a.w);
    h1[0] = f2bf(b.x); h1[1] = f2bf(b.y); h1[2] = f2bf(b.z); h1[3] = f2bf(b.w);
    *(u16x4*)(dst + i) = h0;
    *(u16x4*)(dst + i + 4) = h1;
}

// Kernel 1c: xadapt = bf16(x + svd[d])   (4096x1024)
__global__ __launch_bounds__(256) void xadapt_kernel(
    const float* __restrict__ x, const float* __restrict__ svd,
    unsigned short* __restrict__ out)
{
    const int i = (blockIdx.x * 256 + threadIdx.x) * 8;
    const int d = i & (DIMN - 1);
    float4 a = *(const float4*)(x + i);
    float4 b = *(const float4*)(x + i + 4);
    float4 sa = *(const float4*)(svd + d);
    float4 sb = *(const float4*)(svd + d + 4);
    u16x4 h0, h1;
    h0[0] = f2bf(a.x + sa.x); h0[1] = f2bf(a.y + sa.y);
    h0[2] = f2bf(a.z + sa.z); h0[3] = f2bf(a.w + sa.w);
    h1[0] = f2bf(b.x + sb.x); h1[1] = f2bf(b.y + sb.y);
    h1[2] = f2bf(b.z + sb.z); h1[3] = f2bf(b.w + sb.w);
    *(u16x4*)(out + i) = h0;
    *(u16x4*)(out + i + 4) = h1;
}

// ---------------------------------------------------------------------------
// Kernel 1d: weight fold  W~ = Wq @ Wp  (NN GEMM, fp32 in, bf16 out)
//   Wq [3072,1024] rm, Wp [1024,512] rm -> W~ [3072,512] rm.
//   Rows < 1024 (q-dims) scaled by ATT_SCALE (folds attention scale).
//   A reg-staged fp32->bf16 (rows of Wq); B staged TRANSPOSED into Bs[n][k]
//   (vts-verified key-pair packing pattern). z = branch.
// ---------------------------------------------------------------------------
__global__ __launch_bounds__(256, 2) void wprep_kernel(
    const float* __restrict__ Wq1, const float* __restrict__ Wp1,
    const float* __restrict__ Wq2, const float* __restrict__ Wp2,
    unsigned short* __restrict__ Wt1, unsigned short* __restrict__ Wt2)
{
    const float* Wq = blockIdx.z ? Wq2 : Wq1;
    const float* Wp = blockIdx.z ? Wp2 : Wp1;
    unsigned short* Wt = blockIdx.z ? Wt2 : Wt1;

    __shared__ __align__(16) short As[128 * 64];   // [m][k] swz
    __shared__ __align__(16) short Bs[128 * 64];   // [n][k] swz (B transposed)
    const int tid = threadIdx.x;
    const int m0 = blockIdx.y * 128;
    const int n0 = blockIdx.x * 128;
    const int lane = tid & 63;
    const int wv = tid >> 6;
    const int wr = wv >> 1, wc = wv & 1;
    const int lr = lane & 15;
    const int kg = lane >> 4;

    f32x4 acc[4][4];
    #pragma unroll
    for (int i = 0; i < 4; ++i)
        #pragma unroll
        for (int j = 0; j < 4; ++j)
            acc[i][j] = (f32x4){0.f, 0.f, 0.f, 0.f};

    for (int k0 = 0; k0 < DIMN; k0 += 64) {
        // ---- A: Wq[m0+r][k0 + c4*4 ..] fp32->bf16, swizzled ----
        #pragma unroll
        for (int i = 0; i < 8; ++i) {
            int flat = i * 256 + tid;             // 0..2047
            int r  = flat >> 4;                   // 0..127
            int c4 = flat & 15;
            float4 av = *(const float4*)(Wq + (size_t)(m0 + r) * DIMN + k0 + c4 * 4);
            u16x4 h;
            h[0] = f2bf(av.x); h[1] = f2bf(av.y); h[2] = f2bf(av.z); h[3] = f2bf(av.w);
            int boff = r * 128 + ((((c4 >> 1) ^ (r & 7)) << 4) | ((c4 & 1) << 3));
            *(u16x4*)((char*)As + boff) = h;
        }
        // ---- B transposed: Bs[n][k] <- Wp[k0+2kp(+1)][n0+dg*4+j] ----
        #pragma unroll
        for (int i = 0; i < 4; ++i) {
            int idx = i * 256 + tid;              // 0..1023
            int kp = idx & 31;                    // k-pair
            int dg = idx >> 5;                    // 0..31, 4 cols each
            const float* p0 = Wp + (size_t)(k0 + 2 * kp) * 512 + n0 + dg * 4;
            float4 x0 = *(const float4*)p0;
            float4 x1 = *(const float4*)(p0 + 512);
            float a0[4] = {x0.x, x0.y, x0.z, x0.w};
            float a1[4] = {x1.x, x1.y, x1.z, x1.w};
            #pragma unroll
            for (int j = 0; j < 4; ++j) {
                unsigned pk = (unsigned)f2bf(a0[j]) | ((unsigned)f2bf(a1[j]) << 16);
                int n = dg * 4 + j;
                int boff = n * 128 + ((((kp >> 2) ^ (n & 7)) << 4) | ((kp & 3) << 2));
                *(unsigned*)((char*)Bs + boff) = pk;
            }
        }
        __syncthreads();

        #pragma unroll
        for (int ks = 0; ks < 2; ++ks) {
            bf16x8 a[4], b[4];
            #pragma unroll
            for (int mi = 0; mi < 4; ++mi) {
                int row = wr * 64 + mi * 16 + lr;
                int boff = row * 128 + (((ks * 4 + kg) ^ (row & 7)) << 4);
                a[mi] = *(const bf16x8*)((const char*)As + boff);
            }
            #pragma unroll
            for (int ni = 0; ni < 4; ++ni) {
                int row = wc * 64 + ni * 16 + lr;
                int boff = row * 128 + (((ks * 4 + kg) ^ (row & 7)) << 4);
                b[ni] = *(const bf16x8*)((const char*)Bs + boff);
            }
            #pragma unroll
            for (int mi = 0; mi < 4; ++mi)
                #pragma unroll
                for (int ni = 0; ni < 4; ++ni)
                    acc[mi][ni] = __builtin_amdgcn_mfma_f32_16x16x32_bf16(
                        a[mi], b[ni], acc[mi][ni], 0, 0, 0);
        }
        __syncthreads();
    }

    #pragma unroll
    for (int ni = 0; ni < 4; ++ni) {
        const int col = n0 + wc * 64 + ni * 16 + lr;
        #pragma unroll
        for (int mi = 0; mi < 4; ++mi) {
            const int row = m0 + wr * 64 + mi * 16 + kg * 4;
            #pragma unroll
            for (int r = 0; r < 4; ++r) {
                float sc = (row + r) < DIMN ? ATT_SCALE : 1.f;   // q rows pre-scaled
                Wt[(size_t)(row + r) * 512 + col] = f2bf(acc[mi][ni][r] * sc);
            }
        }
    }
}

// Kernel 1e: b~ = scale_rows(Wq @ b_proj)  [3072] per branch
__global__ __launch_bounds__(256) void bvec_kernel(
    const float* __restrict__ Wq1, const float* __restrict__ bp1,
    const float* __restrict__ Wq2, const float* __restrict__ bp2,
    float* __restrict__ bt1, float* __restrict__ bt2)
{
    const float* Wq = blockIdx.y ? Wq2 : Wq1;
    const float* bp = blockIdx.y ? bp2 : bp1;
    float* bt = blockIdx.y ? bt2 : bt1;
    const int i = blockIdx.x * 256 + threadIdx.x;     // 0..3071
    const float* row = Wq + (size_t)i * DIMN;
    float s = 0.f;
    for (int k = 0; k < DIMN; k += 4) {
        float4 wv = *(const float4*)(row + k);
        float4 bv = *(const float4*)(bp + k);
        s += wv.x * bv.x + wv.y * bv.y + wv.z * bv.z + wv.w * bv.w;
    }
    bt[i] = (i < DIMN ? ATT_SCALE : 1.f) * s;
}

// ---------------------------------------------------------------------------
// Kernel 2a: fused qkv GEMM  qkv_z = x~_z @ W~_z^T + b~_z  (bf16 out)
//   A = xadapt (lda 1024, z picks col half), W~ [3072,512], K=512.
//   blockIdx.z = branch. Staging via global_load_lds, pre-swizzled source.
// ---------------------------------------------------------------------------
__global__ __launch_bounds__(256, 2) void gemm_qkv(
    const unsigned short* __restrict__ xadapt,
    const unsigned short* __restrict__ Wt1,
    const unsigned short* __restrict__ Wt2,
    const float* __restrict__ bt1,
    const float* __restrict__ bt2,
    unsigned short* __restrict__ C1,
    unsigned short* __restrict__ C2)
{
    const unsigned short* A = xadapt + (blockIdx.z ? 512 : 0);  // lda = 1024
    const unsigned short* W = blockIdx.z ? Wt2 : Wt1;           // ldw = 512
    const float* bias = blockIdx.z ? bt2 : bt1;
    unsigned short* C = blockIdx.z ? C2 : C1;                   // ldc = 3072

    __shared__ __align__(16) short As[128 * 64];
    __shared__ __align__(16) short Bs[128 * 64];
    const int tid = threadIdx.x;
    const int m0 = blockIdx.y * 128;
    const int n0 = blockIdx.x * 128;
    const int lane = tid & 63;
    const int wv = tid >> 6;
    const int wr = wv >> 1, wc = wv & 1;
    const int lr = lane & 15;
    const int kg = lane >> 4;

    f32x4 acc[4][4];
    #pragma unroll
    for (int i = 0; i < 4; ++i)
        #pragma unroll
        for (int j = 0; j < 4; ++j)
            acc[i][j] = (f32x4){0.f, 0.f, 0.f, 0.f};

    for (int k0 = 0; k0 < 512; k0 += 64) {
        #pragma unroll
        for (int i = 0; i < 4; ++i) {
            int flat = i * 256 + tid;
            int r = flat >> 3, c = flat & 7;
            int sc = c ^ (r & 7);
            gload_lds16(A + (size_t)(m0 + r) * DIMN + k0 + sc * 8, As + flat * 8);
        }
        #pragma unroll
        for (int i = 0; i < 4; ++i) {
            int flat = i * 256 + tid;
            int r = flat >> 3, c = flat & 7;
            int sc = c ^ (r & 7);
            gload_lds16(W + (size_t)(n0 + r) * 512 + k0 + sc * 8, Bs + flat * 8);
        }
        __syncthreads();

        #pragma unroll
        for (int ks = 0; ks < 2; ++ks) {
            bf16x8 a[4], b[4];
            #pragma unroll
            for (int mi = 0; mi < 4; ++mi) {
                int row = wr * 64 + mi * 16 + lr;
                int boff = row * 128 + (((ks * 4 + kg) ^ (row & 7)) << 4);
                a[mi] = *(const bf16x8*)((const char*)As + boff);
            }
            #pragma unroll
            for (int ni = 0; ni < 4; ++ni) {
                int row = wc * 64 + ni * 16 + lr;
                int boff = row * 128 + (((ks * 4 + kg) ^ (row & 7)) << 4);
                b[ni] = *(const bf16x8*)((const char*)Bs + boff);
            }
            #pragma unroll
            for (int mi = 0; mi < 4; ++mi)
                #pragma unroll
                for (int ni = 0; ni < 4; ++ni)
                    acc[mi][ni] = __builtin_amdgcn_mfma_f32_16x16x32_bf16(
                        a[mi], b[ni], acc[mi][ni], 0, 0, 0);
        }
        __syncthreads();
    }

    #pragma unroll
    for (int ni = 0; ni < 4; ++ni) {
        const int col = n0 + wc * 64 + ni * 16 + lr;
        const float bs = bias[col];
        #pragma unroll
        for (int mi = 0; mi < 4; ++mi) {
            const int row = m0 + wr * 64 + mi * 16 + kg * 4;
            #pragma unroll
            for (int r = 0; r < 4; ++r)
                C[(size_t)(row + r) * BQKV + col] = f2bf(acc[mi][ni][r] + bs);
        }
    }
}

// ---------------------------------------------------------------------------
// Kernel 2b: generic bf16 GEMM C = A @ W^T (+bias), fp32 accum (out-proj).
// ---------------------------------------------------------------------------
__global__ __launch_bounds__(256, 2) void gemm_bf16(
    const unsigned short* __restrict__ A, int lda,
    const unsigned short* __restrict__ W, int ldw,
    const float* __restrict__ bias,
    void* __restrict__ C, int ldc, int K, int out_bf16)
{
    __shared__ __align__(16) short As[128 * 64];
    __shared__ __align__(16) short Bs[128 * 64];
    const int tid = threadIdx.x;
    const int m0 = blockIdx.y * 128;
    const int n0 = blockIdx.x * 128;
    const int lane = tid & 63;
    const int wv = tid >> 6;
    const int wr = wv >> 1, wc = wv & 1;
    const int lr = lane & 15;
    const int kg = lane >> 4;

    f32x4 acc[4][4];
    #pragma unroll
    for (int i = 0; i < 4; ++i)
        #pragma unroll
        for (int j = 0; j < 4; ++j)
            acc[i][j] = (f32x4){0.f, 0.f, 0.f, 0.f};

    for (int k0 = 0; k0 < K; k0 += 64) {
        #pragma unroll
        for (int i = 0; i < 4; ++i) {
            int flat = i * 256 + tid;
            int r = flat >> 3, c = flat & 7;
            int sc = c ^ (r & 7);
            gload_lds16(A + (size_t)(m0 + r) * lda + k0 + sc * 8, As + flat * 8);
        }
        #pragma unroll
        for (int i = 0; i < 4; ++i) {
            int flat = i * 256 + tid;
            int r = flat >> 3, c = flat & 7;
            int sc = c ^ (r & 7);
            gload_lds16(W + (size_t)(n0 + r) * ldw + k0 + sc * 8, Bs + flat * 8);
        }
        __syncthreads();

        #pragma unroll
        for (int ks = 0; ks < 2; ++ks) {
            bf16x8 a[4], b[4];
            #pragma unroll
            for (int mi = 0; mi < 4; ++mi) {
                int row = wr * 64 + mi * 16 + lr;
                int boff = row * 128 + (((ks * 4 + kg) ^ (row & 7)) << 4);
                a[mi] = *(const bf16x8*)((const char*)As + boff);
            }
            #pragma unroll
            for (int ni = 0; ni < 4; ++ni) {
                int row = wc * 64 + ni * 16 + lr;
                int boff = row * 128 + (((ks * 4 + kg) ^ (row & 7)) << 4);
                b[ni] = *(const bf16x8*)((const char*)Bs + boff);
            }
            #pragma unroll
            for (int mi = 0; mi < 4; ++mi)
                #pragma unroll
                for (int ni = 0; ni < 4; ++ni)
                    acc[mi][ni] = __builtin_amdgcn_mfma_f32_16x16x32_bf16(
                        a[mi], b[ni], acc[mi][ni], 0, 0, 0);
        }
        __syncthreads();
    }

    #pragma unroll
    for (int ni = 0; ni < 4; ++ni) {
        const int col = n0 + wc * 64 + ni * 16 + lr;
        const float bs = bias ? bias[col] : 0.f;
        #pragma unroll
        for (int mi = 0; mi < 4; ++mi) {
            const int row = m0 + wr * 64 + mi * 16 + kg * 4;
            #pragma unroll
            for (int r = 0; r < 4; ++r) {
                float v = acc[mi][ni][r] + bs;
                if (out_bf16)
                    ((unsigned short*)C)[(size_t)(row + r) * ldc + col] = f2bf(v);
                else
                    ((float*)C)[(size_t)(row + r) * ldc + col] = v;
            }
        }
    }
}

// ---------------------------------------------------------------------------
// Kernel 3: MFMA differential flash attention, T14 async-staged.
//   Reg-stage K1,K2,V1,V2 for tile t+1 BEFORE computing tile t; write LDS
//   after the post-compute barrier (single-buffered, 2 barriers/tile, HBM
//   latency hidden under QK/softmax/PV). Q pre-scaled in weights.
// ---------------------------------------------------------------------------
__global__ __launch_bounds__(256, 3) void attn_mfma(
    const unsigned short* __restrict__ qkv1,
    const unsigned short* __restrict__ qkv2,
    unsigned short* __restrict__ out)
{
    __shared__ __align__(16) short k1s[64 * 64];       // 8 KB, [key][dim] swz
    __shared__ __align__(16) short k2s[64 * 64];       // 8 KB
    __shared__ __align__(16) short vts[64 * 64];       // 8 KB, [dim][key] swz
    __shared__ __align__(16) short pbufs[4][16 * 64];  // 8 KB, per-wave [q][key] swz

    const int tid = threadIdx.x;
    const int lane = tid & 63;
    const int wv = tid >> 6;
    const int lr = lane & 15;
    const int kg = lane >> 4;
    const int bh = blockIdx.y;
    const int b = bh >> 4, h = bh & 15;
    const int bS = b * SEQ;
    const int q0w = blockIdx.x * 64 + wv * 16;
    short* pw = pbufs[wv];

    // staging registers (tile in flight)
    bf16x8 rk1[2], rk2[2];
    u16x4  rv[2][4];

    const int krow = tid >> 2;               // key row this thread stages
    const int kc4  = tid & 3;                // 16-dim chunk

    auto LOADT = [&](int kt) {
        size_t g = (size_t)(bS + kt + krow) * BQKV + 1024 + h * DHEAD + kc4 * 16;
        rk1[0] = *(const bf16x8*)(qkv1 + g);
        rk1[1] = *(const bf16x8*)(qkv1 + g + 8);
        rk2[0] = *(const bf16x8*)(qkv2 + g);
        rk2[1] = *(const bf16x8*)(qkv2 + g + 8);
        #pragma unroll
        for (int i = 0; i < 2; ++i) {
            int idx = i * 256 + tid;
            int kp = idx & 31, dg = idx >> 5;
            size_t gv = (size_t)(bS + kt + 2 * kp) * BQKV + 2048 + h * DHEAD + dg * 4;
            rv[i][0] = *(const u16x4*)(qkv1 + gv);
            rv[i][1] = *(const u16x4*)(qkv2 + gv);
            rv[i][2] = *(const u16x4*)(qkv1 + gv + BQKV);
            rv[i][3] = *(const u16x4*)(qkv2 + gv + BQKV);
        }
    };
    auto WRITET = [&]() {
        int b0 = krow * 128 + (((kc4 * 2) ^ (krow & 7)) << 4);
        int b1 = krow * 128 + (((kc4 * 2 + 1) ^ (krow & 7)) << 4);
        *(bf16x8*)((char*)k1s + b0) = rk1[0];
        *(bf16x8*)((char*)k1s + b1) = rk1[1];
        *(bf16x8*)((char*)k2s + b0) = rk2[0];
        *(bf16x8*)((char*)k2s + b1) = rk2[1];
        #pragma unroll
        for (int i = 0; i < 2; ++i) {
            int idx = i * 256 + tid;
            int kp = idx & 31, dg = idx >> 5;
            #pragma unroll
            for (int j = 0; j < 4; ++j) {
                float a = 0.5f * (bf2f(rv[i][0][j]) + bf2f(rv[i][1][j]));
                float c = 0.5f * (bf2f(rv[i][2][j]) + bf2f(rv[i][3][j]));
                unsigned pk = (unsigned)f2bf(a) | ((unsigned)f2bf(c) << 16);
                int dim = dg * 4 + j;
                int boff = dim * 128 + ((((kp >> 2) ^ (dim & 7)) << 4) | ((kp & 3) << 2));
                *(unsigned*)((char*)vts + boff) = pk;
            }
        }
    };

    // ---- Q fragments: pre-scaled (folded into W~ q-rows), direct loads ----
    bf16x8 qf1[2], qf2[2];
    {
        const size_t qrow = (size_t)(bS + q0w + lr) * BQKV + h * DHEAD;
        #pragma unroll
        for (int ks = 0; ks < 2; ++ks) {
            qf1[ks] = *(const bf16x8*)(qkv1 + qrow + ks * 32 + kg * 8);
            qf2[ks] = *(const bf16x8*)(qkv2 + qrow + ks * 32 + kg * 8);
        }
    }

    f32x4 o1[4], o2[4];
    #pragma unroll
    for (int i = 0; i < 4; ++i) {
        o1[i] = (f32x4){0.f, 0.f, 0.f, 0.f};
        o2[i] = (f32x4){0.f, 0.f, 0.f, 0.f};
    }
    float m1 = -1e30f, l1 = 0.f, m2 = -1e30f, l2 = 0.f;

    // prologue: stage tile 0
    LOADT(0);
    WRITET();
    __syncthreads();

    for (int kt = 0; kt < SEQ; kt += 64) {
        const bool more = (kt + 64) < SEQ;
        if (more) LOADT(kt + 64);      // loads in flight under compute

        // ---- S^T = K·Q^T ----
        f32x4 s1[4], s2[4];
        #pragma unroll
        for (int f = 0; f < 4; ++f) {
            s1[f] = (f32x4){0.f, 0.f, 0.f, 0.f};
            s2[f] = (f32x4){0.f, 0.f, 0.f, 0.f};
        }
        #pragma unroll
        for (int ks = 0; ks < 2; ++ks) {
            #pragma unroll
            for (int f = 0; f < 4; ++f) {
                int row = f * 16 + lr;
                int boff = row * 128 + (((ks * 4 + kg) ^ (row & 7)) << 4);
                bf16x8 a1 = *(const bf16x8*)((const char*)k1s + boff);
                bf16x8 a2 = *(const bf16x8*)((const char*)k2s + boff);
                s1[f] = __builtin_amdgcn_mfma_f32_16x16x32_bf16(a1, qf1[ks], s1[f], 0, 0, 0);
                s2[f] = __builtin_amdgcn_mfma_f32_16x16x32_bf16(a2, qf2[ks], s2[f], 0, 0, 0);
            }
        }

        // ---- per-branch online softmax + PV ----
        #pragma unroll
        for (int br = 0; br < 2; ++br) {
            f32x4* sf = br ? s2 : s1;
            float& m = br ? m2 : m1;
            float& l = br ? l2 : l1;
            f32x4* oacc = br ? o2 : o1;

            float tm = -1e30f;
            #pragma unroll
            for (int f = 0; f < 4; ++f)
                #pragma unroll
                for (int r = 0; r < 4; ++r) tm = fmaxf(tm, sf[f][r]);
            tm = fmaxf(tm, __shfl_xor(tm, 16));
            tm = fmaxf(tm, __shfl_xor(tm, 32));
            float mnew = fmaxf(m, tm);
            float sc = __expf(m - mnew);
            m = mnew;

            float psum = 0.f;
            #pragma unroll
            for (int f = 0; f < 4; ++f) {
                u16x4 hw;
                #pragma unroll
                for (int r = 0; r < 4; ++r) {
                    float p = __expf(sf[f][r] - mnew);
                    hw[r] = f2bf(p);
                    psum += p;                       // f32 sum (unrounded)
                }
                int boff = lr * 128 + ((((f * 2 + (kg >> 1)) ^ (lr & 7)) << 4) | ((kg & 1) << 3));
                *(u16x4*)((char*)pw + boff) = hw;
            }
            psum += __shfl_xor(psum, 16);
            psum += __shfl_xor(psum, 32);
            l = l * sc + psum;

            #pragma unroll
            for (int r = 0; r < 4; ++r) {
                float scr = __shfl(sc, (kg << 2) | r);
                #pragma unroll
                for (int nf = 0; nf < 4; ++nf) oacc[nf][r] *= scr;
            }

            #pragma unroll
            for (int ks = 0; ks < 2; ++ks) {
                int boffp = lr * 128 + (((ks * 4 + kg) ^ (lr & 7)) << 4);
                bf16x8 ap = *(const bf16x8*)((const char*)pw + boffp);
                #pragma unroll
                for (int nf = 0; nf < 4; ++nf) {
                    int dim = nf * 16 + lr;
                    int boffv = dim * 128 + (((ks * 4 + kg) ^ (dim & 7)) << 4);
                    bf16x8 bv = *(const bf16x8*)((const char*)vts + boffv);
                    oacc[nf] = __builtin_amdgcn_mfma_f32_16x16x32_bf16(ap, bv, oacc[nf], 0, 0, 0);
                }
            }
        }

        __syncthreads();                 // all waves done reading LDS tile t
        if (more) {
            WRITET();                    // vmcnt waits on rk/rv, ds_write t+1
            __syncthreads();             // staging visible
        }
    }

    // ---- epilogue: out = bf16(O1/l1 - O2/l2) ----
    const float inv1 = 1.f / l1, inv2 = 1.f / l2;
    #pragma unroll
    for (int r = 0; r < 4; ++r) {
        float r1 = __shfl(inv1, (kg << 2) | r);
        float r2 = __shfl(inv2, (kg << 2) | r);
        unsigned short* op = out + (size_t)(bS + q0w + kg * 4 + r) * DIMN + h * DHEAD + lr;
        #pragma unroll
        for (int nf = 0; nf < 4; ++nf)
            op[nf * 16] = f2bf(o1[nf][r] * r1 - o2[nf][r] * r2);
    }
}

// ---------------------------------------------------------------------------
// Kernel 4: LayerNorm over last dim (1024), one block per row.
// ---------------------------------------------------------------------------
__global__ __launch_bounds__(256) void ln_kernel(
    const float* __restrict__ X, const float* __restrict__ g,
    const float* __restrict__ bi, float* __restrict__ out)
{
    __shared__ float red[8];
    const int row = blockIdx.x;
    const int tid = threadIdx.x;
    const float* xp = X + (size_t)row * DIMN;
    float4 xv = *(const float4*)(xp + tid * 4);
    float s = xv.x + xv.y + xv.z + xv.w;
    #pragma unroll
    for (int off = 32; off > 0; off >>= 1) s += __shfl_down(s, off);
    const int lane = tid & 63, w = tid >> 6;
    if (lane == 0) red[w] = s;
    __syncthreads();
    const float mu = (red[0] + red[1] + red[2] + red[3]) * (1.f / DIMN);
    const float d0 = xv.x - mu, d1 = xv.y - mu, d2 = xv.z - mu, d3 = xv.w - mu;
    float sq = d0 * d0 + d1 * d1 + d2 * d2 + d3 * d3;
    #pragma unroll
    for (int off = 32; off > 0; off >>= 1) sq += __shfl_down(sq, off);
    if (lane == 0) red[4 + w] = sq;
    __syncthreads();
    const float var = (red[4] + red[5] + red[6] + red[7]) * (1.f / DIMN);
    const float inv = rsqrtf(var + LN_EPS);
    float4 gv = *(const float4*)(g + tid * 4);
    float4 bv = *(const float4*)(bi + tid * 4);
    float4 ov;
    ov.x = d0 * inv * gv.x + bv.x;
    ov.y = d1 * inv * gv.y + bv.y;
    ov.z = d2 * inv * gv.z + bv.z;
    ov.w = d3 * inv * gv.w + bv.w;
    *(float4*)(out + (size_t)row * DIMN + tid * 4) = ov;
}

// ---------------------------------------------------------------------------
// Launch. Workspace (bytes):
//   svd @0 (4K) | bt1 @4K (12K) | bt2 @16K (12K) |
//   woutb @1M (2M) | wt1 @3M (3M) | wt2 @6M (3M) | xadapt @9M (8M) |
//   qkv1b @17M (24M) | qkv2b @41M (24M) | attno @65M (8M) | bufO @73M (16M)
// ---------------------------------------------------------------------------
extern "C" void kernel_launch(void* const* d_in, const int* in_sizes, int n_in,
                              void* d_out, int out_size, void* d_ws, size_t ws_size,
                              hipStream_t stream)
{
    const float* x     = (const float*)d_in[0];
    const float* sigma = (const float*)d_in[1];
    const float* U     = (const float*)d_in[2];
    const float* V     = (const float*)d_in[3];
    const float* Wp1   = (const float*)d_in[4];
    const float* bp1   = (const float*)d_in[5];
    const float* Wp2   = (const float*)d_in[6];
    const float* bp2   = (const float*)d_in[7];
    const float* Wqkv1 = (const float*)d_in[8];
    const float* Wqkv2 = (const float*)d_in[9];
    const float* Wout  = (const float*)d_in[10];
    const float* bout  = (const float*)d_in[11];
    const float* lng   = (const float*)d_in[12];
    const float* lnb   = (const float*)d_in[13];

    const size_t MB = 1024 * 1024;
    char* ws = (char*)d_ws;
    float*          svd    = (float*)(ws);
    float*          bt1    = (float*)(ws + 4096);
    float*          bt2    = (float*)(ws + 16384);
    unsigned short* woutb  = (unsigned short*)(ws + 1 * MB);
    unsigned short* wt1    = (unsigned short*)(ws + 3 * MB);
    unsigned short* wt2    = (unsigned short*)(ws + 6 * MB);
    unsigned short* xadapt = (unsigned short*)(ws + 9 * MB);
    unsigned short* qkv1b  = (unsigned short*)(ws + 17 * MB);
    unsigned short* qkv2b  = (unsigned short*)(ws + 41 * MB);
    unsigned short* attno  = (unsigned short*)(ws + 65 * MB);
    float*          bufO   = (float*)(ws + 73 * MB);

    svd_kernel<<<1, 1024, 0, stream>>>(U, V, sigma, svd);
    xadapt_kernel<<<2048, 256, 0, stream>>>(x, svd, xadapt);

    // weight prep: W~_z = scale_q(Wqkv_z @ Wp_z) bf16, b~_z = scale_q(Wqkv_z @ bp_z)
    wprep_kernel<<<dim3(4, 24, 2), 256, 0, stream>>>(Wqkv1, Wp1, Wqkv2, Wp2, wt1, wt2);
    bvec_kernel<<<dim3(12, 2), 256, 0, stream>>>(Wqkv1, bp1, Wqkv2, bp2, bt1, bt2);
    cvt_kernel<<<512, 256, 0, stream>>>(Wout, woutb);   // 1024*1024

    // fused qkv: qkv_z = x~_z @ W~_z^T + b~_z   (K=512, both branches)
    gemm_qkv<<<dim3(BQKV / 128, NROWS / 128, 2), 256, 0, stream>>>(
        xadapt, wt1, wt2, bt1, bt2, qkv1b, qkv2b);

    // MFMA differential attention -> attno (bf16)
    attn_mfma<<<dim3(SEQ / 64, BATCH * HEADS), 256, 0, stream>>>(qkv1b, qkv2b, attno);

    // out-proj: bufO = attno @ Wout^T + bout (fp32 out)
    gemm_bf16<<<dim3(DIMN / 128, NROWS / 128), 256, 0, stream>>>(
        attno, DIMN, woutb, DIMN, bout, bufO, DIMN, DIMN, 0);

    // LayerNorm -> d_out
    ln_kernel<<<NROWS, 256, 0, stream>>>(bufO, lng, lnb, (float*)d_out);
}

// Round 11
// 392.820 us; speedup vs baseline: 1.0194x; 1.0194x over previous
//
#include <hip/hip_runtime.h>
#include <hip/hip_bf16.h>
#include <math.h>

// Problem constants (fixed by the reference)
#define DIMN   1024
#define HEADS  16
#define DHEAD  64
#define BQKV   3072
#define BATCH  4
#define SEQ    1024
#define NROWS  (BATCH * SEQ)     // 4096
#define ATT_SCALE 0.125f         // 1/sqrt(64), exact power of two
#define LN_EPS 1e-5f

typedef __attribute__((ext_vector_type(8))) short  bf16x8;
typedef __attribute__((ext_vector_type(4))) float  f32x4;
typedef __attribute__((ext_vector_type(4))) unsigned short u16x4;

// fp32 -> bf16 round-to-nearest-even
__device__ __forceinline__ unsigned short f2bf(float f) {
    unsigned u = __float_as_uint(f);
    u += 0x7FFFu + ((u >> 16) & 1u);
    return (unsigned short)(u >> 16);
}
__device__ __forceinline__ float bf2f(unsigned short h) {
    return __uint_as_float((unsigned)h << 16);
}
// async global->LDS 16B copy (wave-uniform dest = base + lane*16)
__device__ __forceinline__ void gload_lds16(const void* g, void* l) {
    __builtin_amdgcn_global_load_lds(
        (const __attribute__((address_space(1))) unsigned int*)g,
        (__attribute__((address_space(3))) unsigned int*)l, 16, 0, 0);
}

// ---------------------------------------------------------------------------
// Kernel 1: svd_adapt[d] = sigma * sum_r U[d,r] * (sum_j V[r,j])
// ---------------------------------------------------------------------------
__global__ __launch_bounds__(1024) void svd_kernel(
    const float* __restrict__ U, const float* __restrict__ V,
    const float* __restrict__ sigma_p, float* __restrict__ svd)
{
    __shared__ float part[16][4];
    __shared__ float vsum[4];
    const int tid = threadIdx.x;          // 0..1023
    float v0 = V[0 * DIMN + tid];
    float v1 = V[1 * DIMN + tid];
    float v2 = V[2 * DIMN + tid];
    float v3 = V[3 * DIMN + tid];
    #pragma unroll
    for (int off = 32; off > 0; off >>= 1) {
        v0 += __shfl_down(v0, off);
        v1 += __shfl_down(v1, off);
        v2 += __shfl_down(v2, off);
        v3 += __shfl_down(v3, off);
    }
    const int lane = tid & 63, w = tid >> 6;
    if (lane == 0) { part[w][0] = v0; part[w][1] = v1; part[w][2] = v2; part[w][3] = v3; }
    __syncthreads();
    if (tid < 4) {
        float s = 0.f;
        #pragma unroll
        for (int i = 0; i < 16; ++i) s += part[i][tid];
        vsum[tid] = s;
    }
    __syncthreads();
    const float sg = sigma_p[0];
    float acc = U[tid * 4 + 0] * vsum[0] + U[tid * 4 + 1] * vsum[1]
              + U[tid * 4 + 2] * vsum[2] + U[tid * 4 + 3] * vsum[3];
    svd[tid] = sg * acc;
}

// ---------------------------------------------------------------------------
// Kernel 1b: fp32 -> bf16 bulk convert (n multiple of 2048) — Wout only
// ---------------------------------------------------------------------------
__global__ __launch_bounds__(256) void cvt_kernel(
    const float* __restrict__ src, unsigned short* __restrict__ dst)
{
    const int i = (blockIdx.x * 256 + threadIdx.x) * 8;
    float4 a = *(const float4*)(src + i);
    float4 b = *(const float4*)(src + i + 4);
    u16x4 h0, h1;
    h0[0] = f2bf(a.x); h0[1] = f2bf(a.y); h0[2] = f2bf(a.z); h0[3] = f2bf(a.w);
    h1[0] = f2bf(b.x); h1[1] = f2bf(b.y); h1[2] = f2bf(b.z); h1[3] = f2bf(b.w);
    *(u16x4*)(dst + i) = h0;
    *(u16x4*)(dst + i + 4) = h1;
}

// Kernel 1c: xadapt = bf16(x + svd[d])   (4096x1024)
__global__ __launch_bounds__(256) void xadapt_kernel(
    const float* __restrict__ x, const float* __restrict__ svd,
    unsigned short* __restrict__ out)
{
    const int i = (blockIdx.x * 256 + threadIdx.x) * 8;
    const int d = i & (DIMN - 1);
    float4 a = *(const float4*)(x + i);
    float4 b = *(const float4*)(x + i + 4);
    float4 sa = *(const float4*)(svd + d);
    float4 sb = *(const float4*)(svd + d + 4);
    u16x4 h0, h1;
    h0[0] = f2bf(a.x + sa.x); h0[1] = f2bf(a.y + sa.y);
    h0[2] = f2bf(a.z + sa.z); h0[3] = f2bf(a.w + sa.w);
    h1[0] = f2bf(b.x + sb.x); h1[1] = f2bf(b.y + sb.y);
    h1[2] = f2bf(b.z + sb.z); h1[3] = f2bf(b.w + sb.w);
    *(u16x4*)(out + i) = h0;
    *(u16x4*)(out + i + 4) = h1;
}

// ---------------------------------------------------------------------------
// Kernel 1d: weight fold  W~ = Wq @ Wp  (NN GEMM, fp32 in, bf16 out)
//   Wq [3072,1024] rm, Wp [1024,512] rm -> W~ [3072,512] rm.
//   Rows < 1024 (q-dims) scaled by ATT_SCALE (folds attention scale).
// ---------------------------------------------------------------------------
__global__ __launch_bounds__(256, 2) void wprep_kernel(
    const float* __restrict__ Wq1, const float* __restrict__ Wp1,
    const float* __restrict__ Wq2, const float* __restrict__ Wp2,
    unsigned short* __restrict__ Wt1, unsigned short* __restrict__ Wt2)
{
    const float* Wq = blockIdx.z ? Wq2 : Wq1;
    const float* Wp = blockIdx.z ? Wp2 : Wp1;
    unsigned short* Wt = blockIdx.z ? Wt2 : Wt1;

    __shared__ __align__(16) short As[128 * 64];   // [m][k] swz
    __shared__ __align__(16) short Bs[128 * 64];   // [n][k] swz (B transposed)
    const int tid = threadIdx.x;
    const int m0 = blockIdx.y * 128;
    const int n0 = blockIdx.x * 128;
    const int lane = tid & 63;
    const int wv = tid >> 6;
    const int wr = wv >> 1, wc = wv & 1;
    const int lr = lane & 15;
    const int kg = lane >> 4;

    f32x4 acc[4][4];
    #pragma unroll
    for (int i = 0; i < 4; ++i)
        #pragma unroll
        for (int j = 0; j < 4; ++j)
            acc[i][j] = (f32x4){0.f, 0.f, 0.f, 0.f};

    for (int k0 = 0; k0 < DIMN; k0 += 64) {
        #pragma unroll
        for (int i = 0; i < 8; ++i) {
            int flat = i * 256 + tid;             // 0..2047
            int r  = flat >> 4;                   // 0..127
            int c4 = flat & 15;
            float4 av = *(const float4*)(Wq + (size_t)(m0 + r) * DIMN + k0 + c4 * 4);
            u16x4 h;
            h[0] = f2bf(av.x); h[1] = f2bf(av.y); h[2] = f2bf(av.z); h[3] = f2bf(av.w);
            int boff = r * 128 + ((((c4 >> 1) ^ (r & 7)) << 4) | ((c4 & 1) << 3));
            *(u16x4*)((char*)As + boff) = h;
        }
        #pragma unroll
        for (int i = 0; i < 4; ++i) {
            int idx = i * 256 + tid;              // 0..1023
            int kp = idx & 31;
            int dg = idx >> 5;
            const float* p0 = Wp + (size_t)(k0 + 2 * kp) * 512 + n0 + dg * 4;
            float4 x0 = *(const float4*)p0;
            float4 x1 = *(const float4*)(p0 + 512);
            float a0[4] = {x0.x, x0.y, x0.z, x0.w};
            float a1[4] = {x1.x, x1.y, x1.z, x1.w};
            #pragma unroll
            for (int j = 0; j < 4; ++j) {
                unsigned pk = (unsigned)f2bf(a0[j]) | ((unsigned)f2bf(a1[j]) << 16);
                int n = dg * 4 + j;
                int boff = n * 128 + ((((kp >> 2) ^ (n & 7)) << 4) | ((kp & 3) << 2));
                *(unsigned*)((char*)Bs + boff) = pk;
            }
        }
        __syncthreads();

        #pragma unroll
        for (int ks = 0; ks < 2; ++ks) {
            bf16x8 a[4], b[4];
            #pragma unroll
            for (int mi = 0; mi < 4; ++mi) {
                int row = wr * 64 + mi * 16 + lr;
                int boff = row * 128 + (((ks * 4 + kg) ^ (row & 7)) << 4);
                a[mi] = *(const bf16x8*)((const char*)As + boff);
            }
            #pragma unroll
            for (int ni = 0; ni < 4; ++ni) {
                int row = wc * 64 + ni * 16 + lr;
                int boff = row * 128 + (((ks * 4 + kg) ^ (row & 7)) << 4);
                b[ni] = *(const bf16x8*)((const char*)Bs + boff);
            }
            #pragma unroll
            for (int mi = 0; mi < 4; ++mi)
                #pragma unroll
                for (int ni = 0; ni < 4; ++ni)
                    acc[mi][ni] = __builtin_amdgcn_mfma_f32_16x16x32_bf16(
                        a[mi], b[ni], acc[mi][ni], 0, 0, 0);
        }
        __syncthreads();
    }

    #pragma unroll
    for (int ni = 0; ni < 4; ++ni) {
        const int col = n0 + wc * 64 + ni * 16 + lr;
        #pragma unroll
        for (int mi = 0; mi < 4; ++mi) {
            const int row = m0 + wr * 64 + mi * 16 + kg * 4;
            #pragma unroll
            for (int r = 0; r < 4; ++r) {
                float sc = (row + r) < DIMN ? ATT_SCALE : 1.f;   // q rows pre-scaled
                Wt[(size_t)(row + r) * 512 + col] = f2bf(acc[mi][ni][r] * sc);
            }
        }
    }
}

// Kernel 1e: b~ = scale_rows(Wq @ b_proj) — wave-per-output (was 96-wave
// serial-chain latency bomb: 0.4 waves/CU, 1024-FMA dependent chain/thread).
__global__ __launch_bounds__(256) void bvec_kernel(
    const float* __restrict__ Wq1, const float* __restrict__ bp1,
    const float* __restrict__ Wq2, const float* __restrict__ bp2,
    float* __restrict__ bt1, float* __restrict__ bt2)
{
    const float* Wq = blockIdx.y ? Wq2 : Wq1;
    const float* bp = blockIdx.y ? bp2 : bp1;
    float* bt = blockIdx.y ? bt2 : bt1;
    const int wv = threadIdx.x >> 6, lane = threadIdx.x & 63;
    const int i = blockIdx.x * 4 + wv;               // output row 0..3071
    const float* row = Wq + (size_t)i * DIMN + lane * 16;
    const float* bv = bp + lane * 16;
    float s = 0.f;
    #pragma unroll
    for (int j = 0; j < 4; ++j) {
        float4 w4 = *(const float4*)(row + j * 4);
        float4 b4 = *(const float4*)(bv + j * 4);
        s += w4.x * b4.x + w4.y * b4.y + w4.z * b4.z + w4.w * b4.w;
    }
    #pragma unroll
    for (int off = 32; off > 0; off >>= 1) s += __shfl_down(s, off);
    if (lane == 0) bt[i] = (i < DIMN ? ATT_SCALE : 1.f) * s;
}

// ---------------------------------------------------------------------------
// Kernel 2a: fused qkv GEMM  qkv_z = x~_z @ W~_z^T + b~_z  (bf16 out)
// ---------------------------------------------------------------------------
__global__ __launch_bounds__(256, 2) void gemm_qkv(
    const unsigned short* __restrict__ xadapt,
    const unsigned short* __restrict__ Wt1,
    const unsigned short* __restrict__ Wt2,
    const float* __restrict__ bt1,
    const float* __restrict__ bt2,
    unsigned short* __restrict__ C1,
    unsigned short* __restrict__ C2)
{
    const unsigned short* A = xadapt + (blockIdx.z ? 512 : 0);  // lda = 1024
    const unsigned short* W = blockIdx.z ? Wt2 : Wt1;           // ldw = 512
    const float* bias = blockIdx.z ? bt2 : bt1;
    unsigned short* C = blockIdx.z ? C2 : C1;                   // ldc = 3072

    __shared__ __align__(16) short As[128 * 64];
    __shared__ __align__(16) short Bs[128 * 64];
    const int tid = threadIdx.x;
    const int m0 = blockIdx.y * 128;
    const int n0 = blockIdx.x * 128;
    const int lane = tid & 63;
    const int wv = tid >> 6;
    const int wr = wv >> 1, wc = wv & 1;
    const int lr = lane & 15;
    const int kg = lane >> 4;

    f32x4 acc[4][4];
    #pragma unroll
    for (int i = 0; i < 4; ++i)
        #pragma unroll
        for (int j = 0; j < 4; ++j)
            acc[i][j] = (f32x4){0.f, 0.f, 0.f, 0.f};

    for (int k0 = 0; k0 < 512; k0 += 64) {
        #pragma unroll
        for (int i = 0; i < 4; ++i) {
            int flat = i * 256 + tid;
            int r = flat >> 3, c = flat & 7;
            int sc = c ^ (r & 7);
            gload_lds16(A + (size_t)(m0 + r) * DIMN + k0 + sc * 8, As + flat * 8);
        }
        #pragma unroll
        for (int i = 0; i < 4; ++i) {
            int flat = i * 256 + tid;
            int r = flat >> 3, c = flat & 7;
            int sc = c ^ (r & 7);
            gload_lds16(W + (size_t)(n0 + r) * 512 + k0 + sc * 8, Bs + flat * 8);
        }
        __syncthreads();

        #pragma unroll
        for (int ks = 0; ks < 2; ++ks) {
            bf16x8 a[4], b[4];
            #pragma unroll
            for (int mi = 0; mi < 4; ++mi) {
                int row = wr * 64 + mi * 16 + lr;
                int boff = row * 128 + (((ks * 4 + kg) ^ (row & 7)) << 4);
                a[mi] = *(const bf16x8*)((const char*)As + boff);
            }
            #pragma unroll
            for (int ni = 0; ni < 4; ++ni) {
                int row = wc * 64 + ni * 16 + lr;
                int boff = row * 128 + (((ks * 4 + kg) ^ (row & 7)) << 4);
                b[ni] = *(const bf16x8*)((const char*)Bs + boff);
            }
            #pragma unroll
            for (int mi = 0; mi < 4; ++mi)
                #pragma unroll
                for (int ni = 0; ni < 4; ++ni)
                    acc[mi][ni] = __builtin_amdgcn_mfma_f32_16x16x32_bf16(
                        a[mi], b[ni], acc[mi][ni], 0, 0, 0);
        }
        __syncthreads();
    }

    #pragma unroll
    for (int ni = 0; ni < 4; ++ni) {
        const int col = n0 + wc * 64 + ni * 16 + lr;
        const float bs = bias[col];
        #pragma unroll
        for (int mi = 0; mi < 4; ++mi) {
            const int row = m0 + wr * 64 + mi * 16 + kg * 4;
            #pragma unroll
            for (int r = 0; r < 4; ++r)
                C[(size_t)(row + r) * BQKV + col] = f2bf(acc[mi][ni][r] + bs);
        }
    }
}

// ---------------------------------------------------------------------------
// Kernel 2b: generic bf16 GEMM C = A @ W^T (+bias), fp32 accum (out-proj).
// ---------------------------------------------------------------------------
__global__ __launch_bounds__(256, 2) void gemm_bf16(
    const unsigned short* __restrict__ A, int lda,
    const unsigned short* __restrict__ W, int ldw,
    const float* __restrict__ bias,
    void* __restrict__ C, int ldc, int K, int out_bf16)
{
    __shared__ __align__(16) short As[128 * 64];
    __shared__ __align__(16) short Bs[128 * 64];
    const int tid = threadIdx.x;
    const int m0 = blockIdx.y * 128;
    const int n0 = blockIdx.x * 128;
    const int lane = tid & 63;
    const int wv = tid >> 6;
    const int wr = wv >> 1, wc = wv & 1;
    const int lr = lane & 15;
    const int kg = lane >> 4;

    f32x4 acc[4][4];
    #pragma unroll
    for (int i = 0; i < 4; ++i)
        #pragma unroll
        for (int j = 0; j < 4; ++j)
            acc[i][j] = (f32x4){0.f, 0.f, 0.f, 0.f};

    for (int k0 = 0; k0 < K; k0 += 64) {
        #pragma unroll
        for (int i = 0; i < 4; ++i) {
            int flat = i * 256 + tid;
            int r = flat >> 3, c = flat & 7;
            int sc = c ^ (r & 7);
            gload_lds16(A + (size_t)(m0 + r) * lda + k0 + sc * 8, As + flat * 8);
        }
        #pragma unroll
        for (int i = 0; i < 4; ++i) {
            int flat = i * 256 + tid;
            int r = flat >> 3, c = flat & 7;
            int sc = c ^ (r & 7);
            gload_lds16(W + (size_t)(n0 + r) * ldw + k0 + sc * 8, Bs + flat * 8);
        }
        __syncthreads();

        #pragma unroll
        for (int ks = 0; ks < 2; ++ks) {
            bf16x8 a[4], b[4];
            #pragma unroll
            for (int mi = 0; mi < 4; ++mi) {
                int row = wr * 64 + mi * 16 + lr;
                int boff = row * 128 + (((ks * 4 + kg) ^ (row & 7)) << 4);
                a[mi] = *(const bf16x8*)((const char*)As + boff);
            }
            #pragma unroll
            for (int ni = 0; ni < 4; ++ni) {
                int row = wc * 64 + ni * 16 + lr;
                int boff = row * 128 + (((ks * 4 + kg) ^ (row & 7)) << 4);
                b[ni] = *(const bf16x8*)((const char*)Bs + boff);
            }
            #pragma unroll
            for (int mi = 0; mi < 4; ++mi)
                #pragma unroll
                for (int ni = 0; ni < 4; ++ni)
                    acc[mi][ni] = __builtin_amdgcn_mfma_f32_16x16x32_bf16(
                        a[mi], b[ni], acc[mi][ni], 0, 0, 0);
        }
        __syncthreads();
    }

    #pragma unroll
    for (int ni = 0; ni < 4; ++ni) {
        const int col = n0 + wc * 64 + ni * 16 + lr;
        const float bs = bias ? bias[col] : 0.f;
        #pragma unroll
        for (int mi = 0; mi < 4; ++mi) {
            const int row = m0 + wr * 64 + mi * 16 + kg * 4;
            #pragma unroll
            for (int r = 0; r < 4; ++r) {
                float v = acc[mi][ni][r] + bs;
                if (out_bf16)
                    ((unsigned short*)C)[(size_t)(row + r) * ldc + col] = f2bf(v);
                else
                    ((float*)C)[(size_t)(row + r) * ldc + col] = v;
            }
        }
    }
}

// ---------------------------------------------------------------------------
// Kernel 3: MFMA differential flash attention, T14 async-staged.
//   This round: branch-SEQUENTIAL S computation (live S regs 32->16 f32)
//   to cut register pressure and raise occupancy (was 24% at VGPR 84+acc).
// ---------------------------------------------------------------------------
__global__ __launch_bounds__(256, 3) void attn_mfma(
    const unsigned short* __restrict__ qkv1,
    const unsigned short* __restrict__ qkv2,
    unsigned short* __restrict__ out)
{
    __shared__ __align__(16) short k1s[64 * 64];       // 8 KB, [key][dim] swz
    __shared__ __align__(16) short k2s[64 * 64];       // 8 KB
    __shared__ __align__(16) short vts[64 * 64];       // 8 KB, [dim][key] swz
    __shared__ __align__(16) short pbufs[4][16 * 64];  // 8 KB, per-wave [q][key] swz

    const int tid = threadIdx.x;
    const int lane = tid & 63;
    const int wv = tid >> 6;
    const int lr = lane & 15;
    const int kg = lane >> 4;
    const int bh = blockIdx.y;
    const int b = bh >> 4, h = bh & 15;
    const int bS = b * SEQ;
    const int q0w = blockIdx.x * 64 + wv * 16;
    short* pw = pbufs[wv];

    // staging registers (tile in flight)
    bf16x8 rk1[2], rk2[2];
    u16x4  rv[2][4];

    const int krow = tid >> 2;               // key row this thread stages
    const int kc4  = tid & 3;                // 16-dim chunk

    auto LOADT = [&](int kt) {
        size_t g = (size_t)(bS + kt + krow) * BQKV + 1024 + h * DHEAD + kc4 * 16;
        rk1[0] = *(const bf16x8*)(qkv1 + g);
        rk1[1] = *(const bf16x8*)(qkv1 + g + 8);
        rk2[0] = *(const bf16x8*)(qkv2 + g);
        rk2[1] = *(const bf16x8*)(qkv2 + g + 8);
        #pragma unroll
        for (int i = 0; i < 2; ++i) {
            int idx = i * 256 + tid;
            int kp = idx & 31, dg = idx >> 5;
            size_t gv = (size_t)(bS + kt + 2 * kp) * BQKV + 2048 + h * DHEAD + dg * 4;
            rv[i][0] = *(const u16x4*)(qkv1 + gv);
            rv[i][1] = *(const u16x4*)(qkv2 + gv);
            rv[i][2] = *(const u16x4*)(qkv1 + gv + BQKV);
            rv[i][3] = *(const u16x4*)(qkv2 + gv + BQKV);
        }
    };
    auto WRITET = [&]() {
        int b0 = krow * 128 + (((kc4 * 2) ^ (krow & 7)) << 4);
        int b1 = krow * 128 + (((kc4 * 2 + 1) ^ (krow & 7)) << 4);
        *(bf16x8*)((char*)k1s + b0) = rk1[0];
        *(bf16x8*)((char*)k1s + b1) = rk1[1];
        *(bf16x8*)((char*)k2s + b0) = rk2[0];
        *(bf16x8*)((char*)k2s + b1) = rk2[1];
        #pragma unroll
        for (int i = 0; i < 2; ++i) {
            int idx = i * 256 + tid;
            int kp = idx & 31, dg = idx >> 5;
            #pragma unroll
            for (int j = 0; j < 4; ++j) {
                float a = 0.5f * (bf2f(rv[i][0][j]) + bf2f(rv[i][1][j]));
                float c = 0.5f * (bf2f(rv[i][2][j]) + bf2f(rv[i][3][j]));
                unsigned pk = (unsigned)f2bf(a) | ((unsigned)f2bf(c) << 16);
                int dim = dg * 4 + j;
                int boff = dim * 128 + ((((kp >> 2) ^ (dim & 7)) << 4) | ((kp & 3) << 2));
                *(unsigned*)((char*)vts + boff) = pk;
            }
        }
    };

    // ---- Q fragments: pre-scaled (folded into W~ q-rows), direct loads ----
    bf16x8 qf1[2], qf2[2];
    {
        const size_t qrow = (size_t)(bS + q0w + lr) * BQKV + h * DHEAD;
        #pragma unroll
        for (int ks = 0; ks < 2; ++ks) {
            qf1[ks] = *(const bf16x8*)(qkv1 + qrow + ks * 32 + kg * 8);
            qf2[ks] = *(const bf16x8*)(qkv2 + qrow + ks * 32 + kg * 8);
        }
    }

    f32x4 o1[4], o2[4];
    #pragma unroll
    for (int i = 0; i < 4; ++i) {
        o1[i] = (f32x4){0.f, 0.f, 0.f, 0.f};
        o2[i] = (f32x4){0.f, 0.f, 0.f, 0.f};
    }
    float m1 = -1e30f, l1 = 0.f, m2 = -1e30f, l2 = 0.f;

    // prologue: stage tile 0
    LOADT(0);
    WRITET();
    __syncthreads();

    for (int kt = 0; kt < SEQ; kt += 64) {
        const bool more = (kt + 64) < SEQ;
        if (more) LOADT(kt + 64);      // loads in flight under compute

        // ---- per-branch: S^T = K·Q^T, softmax, PV (sequential branches) ----
        #pragma unroll
        for (int br = 0; br < 2; ++br) {
            const short* ksrc = br ? k2s : k1s;
            const bf16x8* qf = br ? qf2 : qf1;
            float& m = br ? m2 : m1;
            float& l = br ? l2 : l1;
            f32x4* oacc = br ? o2 : o1;

            f32x4 sf[4];
            #pragma unroll
            for (int f = 0; f < 4; ++f) sf[f] = (f32x4){0.f, 0.f, 0.f, 0.f};
            #pragma unroll
            for (int ks = 0; ks < 2; ++ks) {
                #pragma unroll
                for (int f = 0; f < 4; ++f) {
                    int row = f * 16 + lr;
                    int boff = row * 128 + (((ks * 4 + kg) ^ (row & 7)) << 4);
                    bf16x8 af = *(const bf16x8*)((const char*)ksrc + boff);
                    sf[f] = __builtin_amdgcn_mfma_f32_16x16x32_bf16(af, qf[ks], sf[f], 0, 0, 0);
                }
            }

            float tm = -1e30f;
            #pragma unroll
            for (int f = 0; f < 4; ++f)
                #pragma unroll
                for (int r = 0; r < 4; ++r) tm = fmaxf(tm, sf[f][r]);
            tm = fmaxf(tm, __shfl_xor(tm, 16));
            tm = fmaxf(tm, __shfl_xor(tm, 32));
            float mnew = fmaxf(m, tm);
            float sc = __expf(m - mnew);
            m = mnew;

            float psum = 0.f;
            #pragma unroll
            for (int f = 0; f < 4; ++f) {
                u16x4 hw;
                #pragma unroll
                for (int r = 0; r < 4; ++r) {
                    float p = __expf(sf[f][r] - mnew);
                    hw[r] = f2bf(p);
                    psum += p;
                }
                int boff = lr * 128 + ((((f * 2 + (kg >> 1)) ^ (lr & 7)) << 4) | ((kg & 1) << 3));
                *(u16x4*)((char*)pw + boff) = hw;
            }
            psum += __shfl_xor(psum, 16);
            psum += __shfl_xor(psum, 32);
            l = l * sc + psum;

            #pragma unroll
            for (int r = 0; r < 4; ++r) {
                float scr = __shfl(sc, (kg << 2) | r);
                #pragma unroll
                for (int nf = 0; nf < 4; ++nf) oacc[nf][r] *= scr;
            }

            #pragma unroll
            for (int ks = 0; ks < 2; ++ks) {
                int boffp = lr * 128 + (((ks * 4 + kg) ^ (lr & 7)) << 4);
                bf16x8 ap = *(const bf16x8*)((const char*)pw + boffp);
                #pragma unroll
                for (int nf = 0; nf < 4; ++nf) {
                    int dim = nf * 16 + lr;
                    int boffv = dim * 128 + (((ks * 4 + kg) ^ (dim & 7)) << 4);
                    bf16x8 bv = *(const bf16x8*)((const char*)vts + boffv);
                    oacc[nf] = __builtin_amdgcn_mfma_f32_16x16x32_bf16(ap, bv, oacc[nf], 0, 0, 0);
                }
            }
        }

        __syncthreads();                 // all waves done reading LDS tile t
        if (more) {
            WRITET();                    // vmcnt waits on rk/rv, ds_write t+1
            __syncthreads();             // staging visible
        }
    }

    // ---- epilogue: out = bf16(O1/l1 - O2/l2) ----
    const float inv1 = 1.f / l1, inv2 = 1.f / l2;
    #pragma unroll
    for (int r = 0; r < 4; ++r) {
        float r1 = __shfl(inv1, (kg << 2) | r);
        float r2 = __shfl(inv2, (kg << 2) | r);
        unsigned short* op = out + (size_t)(bS + q0w + kg * 4 + r) * DIMN + h * DHEAD + lr;
        #pragma unroll
        for (int nf = 0; nf < 4; ++nf)
            op[nf * 16] = f2bf(o1[nf][r] * r1 - o2[nf][r] * r2);
    }
}

// ---------------------------------------------------------------------------
// Kernel 4: LayerNorm over last dim (1024), one block per row.
// ---------------------------------------------------------------------------
__global__ __launch_bounds__(256) void ln_kernel(
    const float* __restrict__ X, const float* __restrict__ g,
    const float* __restrict__ bi, float* __restrict__ out)
{
    __shared__ float red[8];
    const int row = blockIdx.x;
    const int tid = threadIdx.x;
    const float* xp = X + (size_t)row * DIMN;
    float4 xv = *(const float4*)(xp + tid * 4);
    float s = xv.x + xv.y + xv.z + xv.w;
    #pragma unroll
    for (int off = 32; off > 0; off >>= 1) s += __shfl_down(s, off);
    const int lane = tid & 63, w = tid >> 6;
    if (lane == 0) red[w] = s;
    __syncthreads();
    const float mu = (red[0] + red[1] + red[2] + red[3]) * (1.f / DIMN);
    const float d0 = xv.x - mu, d1 = xv.y - mu, d2 = xv.z - mu, d3 = xv.w - mu;
    float sq = d0 * d0 + d1 * d1 + d2 * d2 + d3 * d3;
    #pragma unroll
    for (int off = 32; off > 0; off >>= 1) sq += __shfl_down(sq, off);
    if (lane == 0) red[4 + w] = sq;
    __syncthreads();
    const float var = (red[4] + red[5] + red[6] + red[7]) * (1.f / DIMN);
    const float inv = rsqrtf(var + LN_EPS);
    float4 gv = *(const float4*)(g + tid * 4);
    float4 bv = *(const float4*)(bi + tid * 4);
    float4 ov;
    ov.x = d0 * inv * gv.x + bv.x;
    ov.y = d1 * inv * gv.y + bv.y;
    ov.z = d2 * inv * gv.z + bv.z;
    ov.w = d3 * inv * gv.w + bv.w;
    *(float4*)(out + (size_t)row * DIMN + tid * 4) = ov;
}

// ---------------------------------------------------------------------------
// Launch. Workspace (bytes):
//   svd @0 (4K) | bt1 @4K (12K) | bt2 @16K (12K) |
//   woutb @1M (2M) | wt1 @3M (3M) | wt2 @6M (3M) | xadapt @9M (8M) |
//   qkv1b @17M (24M) | qkv2b @41M (24M) | attno @65M (8M) | bufO @73M (16M)
// ---------------------------------------------------------------------------
extern "C" void kernel_launch(void* const* d_in, const int* in_sizes, int n_in,
                              void* d_out, int out_size, void* d_ws, size_t ws_size,
                              hipStream_t stream)
{
    const float* x     = (const float*)d_in[0];
    const float* sigma = (const float*)d_in[1];
    const float* U     = (const float*)d_in[2];
    const float* V     = (const float*)d_in[3];
    const float* Wp1   = (const float*)d_in[4];
    const float* bp1   = (const float*)d_in[5];
    const float* Wp2   = (const float*)d_in[6];
    const float* bp2   = (const float*)d_in[7];
    const float* Wqkv1 = (const float*)d_in[8];
    const float* Wqkv2 = (const float*)d_in[9];
    const float* Wout  = (const float*)d_in[10];
    const float* bout  = (const float*)d_in[11];
    const float* lng   = (const float*)d_in[12];
    const float* lnb   = (const float*)d_in[13];

    const size_t MB = 1024 * 1024;
    char* ws = (char*)d_ws;
    float*          svd    = (float*)(ws);
    float*          bt1    = (float*)(ws + 4096);
    float*          bt2    = (float*)(ws + 16384);
    unsigned short* woutb  = (unsigned short*)(ws + 1 * MB);
    unsigned short* wt1    = (unsigned short*)(ws + 3 * MB);
    unsigned short* wt2    = (unsigned short*)(ws + 6 * MB);
    unsigned short* xadapt = (unsigned short*)(ws + 9 * MB);
    unsigned short* qkv1b  = (unsigned short*)(ws + 17 * MB);
    unsigned short* qkv2b  = (unsigned short*)(ws + 41 * MB);
    unsigned short* attno  = (unsigned short*)(ws + 65 * MB);
    float*          bufO   = (float*)(ws + 73 * MB);

    svd_kernel<<<1, 1024, 0, stream>>>(U, V, sigma, svd);
    xadapt_kernel<<<2048, 256, 0, stream>>>(x, svd, xadapt);

    // weight prep: W~_z = scale_q(Wqkv_z @ Wp_z) bf16, b~_z = scale_q(Wqkv_z @ bp_z)
    wprep_kernel<<<dim3(4, 24, 2), 256, 0, stream>>>(Wqkv1, Wp1, Wqkv2, Wp2, wt1, wt2);
    bvec_kernel<<<dim3(768, 2), 256, 0, stream>>>(Wqkv1, bp1, Wqkv2, bp2, bt1, bt2);
    cvt_kernel<<<512, 256, 0, stream>>>(Wout, woutb);   // 1024*1024

    // fused qkv: qkv_z = x~_z @ W~_z^T + b~_z   (K=512, both branches)
    gemm_qkv<<<dim3(BQKV / 128, NROWS / 128, 2), 256, 0, stream>>>(
        xadapt, wt1, wt2, bt1, bt2, qkv1b, qkv2b);

    // MFMA differential attention -> attno (bf16)
    attn_mfma<<<dim3(SEQ / 64, BATCH * HEADS), 256, 0, stream>>>(qkv1b, qkv2b, attno);

    // out-proj: bufO = attno @ Wout^T + bout (fp32 out)
    gemm_bf16<<<dim3(DIMN / 128, NROWS / 128), 256, 0, stream>>>(
        attno, DIMN, woutb, DIMN, bout, bufO, DIMN, DIMN, 0);

    // LayerNorm -> d_out
    ln_kernel<<<NROWS, 256, 0, stream>>>(bufO, lng, lnb, (float*)d_out);
}